// Round 5
// baseline (602.696 us; speedup 1.0000x reference)
//
#include <hip/hip_runtime.h>
#include <stdint.h>

// Problem constants (fixed by setup_inputs): B=2, C=32, H=W=D=96, N=30000
#define HWD 884736ull          // 96*96*96
#define NV 30000               // vertices per batch
#define NVT 60000              // total vertices
#define AST 1032               // LDS A-tile row stride (shorts); breaks pow2 strides
#define NBKT 192               // buckets: batch(2) x z-voxel(96)

typedef __attribute__((ext_vector_type(8))) __bf16 bf16x8;
typedef __attribute__((ext_vector_type(4))) float f32x4;
typedef __attribute__((ext_vector_type(2))) unsigned int uint2v;
typedef __attribute__((ext_vector_type(4))) unsigned int uint4v;

__device__ __forceinline__ unsigned short f2bf(float f) {
    union { float f; unsigned int u; } v; v.f = f;
    unsigned int u = v.u;
    return (unsigned short)((u + 0x7FFFu + ((u >> 16) & 1u)) >> 16);  // RNE
}

__device__ __forceinline__ float bf_lo(unsigned int u) {
    union { unsigned int u; float f; } v; v.u = u << 16; return v.f;
}
__device__ __forceinline__ float bf_hi(unsigned int u) {
    union { unsigned int u; float f; } v; v.u = u & 0xffff0000u; return v.f;
}

// bucket key: batch * 96 + floor(z voxel coord) — pure locality heuristic
__device__ __forceinline__ int bucket_key(const float* __restrict__ verts, int v) {
    float z = verts[(size_t)v * 3 + 2];
    float iz = fminf(fmaxf((z + 1.0f) * 0.5f * 95.0f, 0.0f), 95.0f);
    int zv = min((int)iz, 95);
    int b = (v >= NV) ? 1 : 0;
    return b * 96 + zv;
}

// Per-axis: replicate reference clamp/floor math for shifts {-1,0,1}, then fold
// into 4-wide window weights. Window start ws = clamp(x0_center-1, 0, 92).
__device__ __forceinline__ void axis_setup(float coord, float sc, int& wstart, float w[3][4]) {
    int i0[3], i1[3];
    float fr[3];
#pragma unroll
    for (int a = 0; a < 3; ++a) {
        float g = coord + (float)(a - 1) * sc;
        float ix = (g + 1.0f) * 0.5f * 95.0f;
        ix = fminf(fmaxf(ix, 0.0f), 95.0f);
        float fl = floorf(ix);
        int x0 = (int)fl;
        i0[a] = x0;
        i1[a] = min(x0 + 1, 95);
        fr[a] = ix - fl;
    }
    int ws = min(max(i0[1] - 1, 0), 92);
    wstart = ws;
#pragma unroll
    for (int a = 0; a < 3; ++a) {
        int d0 = min(max(i0[a] - ws, 0), 3);
        int d1 = min(max(i1[a] - ws, 0), 3);
        float f1 = fr[a], f0 = 1.0f - f1;
#pragma unroll
        for (int j = 0; j < 4; ++j)
            w[a][j] = (d0 == j ? f0 : 0.0f) + (d1 == j ? f1 : 0.0f);
    }
}

// Pack conv_w (32,32,1,27) fp32 -> bf16 B-fragments for mfma_f32_16x16x32_bf16.
// element j of wp[(s*2+t)*64 + lane] is B[k = s*32 + (lane>>4)*8 + j][o = t*16 + (lane&15)]
__global__ __launch_bounds__(256) void prep_kernel(const float* __restrict__ cw,
                                                   unsigned short* __restrict__ Wp) {
    int gid = blockIdx.x * 256 + threadIdx.x;  // 0..32767
    int j = gid & 7;
    int l = (gid >> 3) & 63;
    int t = (gid >> 9) & 1;
    int s = gid >> 10;
    int kk = ((l >> 4) & 3) * 8 + j;
    int o = t * 16 + (l & 15);
    float v = 0.0f;
    if (kk < 27) v = cw[(size_t)o * 864 + s * 27 + kk];
    Wp[gid] = f2bf(v);
}

// (B,C,H,W,D) fp32 -> x-quad-packed bf16: voxQ[((b*9216+zy)*24 + q)*32 + c] is a
// uint2 holding taps x = 4q..4q+3 of channel c (2 bf16 per uint, low = even x).
__global__ __launch_bounds__(256) void transpose_kernel(const float* __restrict__ vox,
                                                        uint2v* __restrict__ voxQ) {
    int blk = blockIdx.x;            // 0..18431 encodes (b, zy)
    int tid = threadIdx.x;
    int b = blk / 9216;
    int zy = blk % 9216;
    const float* src = vox + (size_t)b * 32 * HWD + (size_t)zy * 96;
    uint2v* dst = voxQ + (size_t)blk * 768;
#pragma unroll
    for (int i = 0; i < 3; ++i) {
        int idx = i * 256 + tid;     // 0..767
        int c = idx & 31;
        int q = idx >> 5;            // 0..23
        f32x4 v = *(const f32x4*)(src + (size_t)c * HWD + q * 4);
        unsigned int u0 = (unsigned int)f2bf(v[0]) | ((unsigned int)f2bf(v[1]) << 16);
        unsigned int u1 = (unsigned int)f2bf(v[2]) | ((unsigned int)f2bf(v[3]) << 16);
        uint2v p = {u0, u1};
        dst[q * 32 + c] = p;
    }
}

// Counting sort pass 1: single block. Histogram 192 buckets in LDS, serial
// exclusive scan, write starts (unused) and atomic cursors to ws.
__global__ __launch_bounds__(256) void count_kernel(const float* __restrict__ verts,
                                                    int* __restrict__ cursors) {
    __shared__ int hist[NBKT];
    __shared__ int scan[NBKT];
    int tid = threadIdx.x;
    for (int i = tid; i < NBKT; i += 256) hist[i] = 0;
    __syncthreads();
    for (int v = tid; v < NVT; v += 256)
        atomicAdd(&hist[bucket_key(verts, v)], 1);
    __syncthreads();
    if (tid == 0) {
        int acc = 0;
        for (int i = 0; i < NBKT; ++i) { scan[i] = acc; acc += hist[i]; }
    }
    __syncthreads();
    for (int i = tid; i < NBKT; i += 256) cursors[i] = scan[i];
}

// Counting sort pass 2: scatter vertex ids into perm by bucket order.
__global__ __launch_bounds__(256) void scatter_kernel(const float* __restrict__ verts,
                                                      int* __restrict__ cursors,
                                                      int* __restrict__ perm) {
    int v = blockIdx.x * 256 + threadIdx.x;
    if (v >= NVT) return;
    int pos = atomicAdd(&cursors[bucket_key(verts, v)], 1);
    perm[pos] = v;
}

// Fused sample + GEMM. Block = 512 threads = 16 vertices x 32 channels.
// Vertices taken in bucket-sorted order via perm[] (z-slab locality -> the
// in-flight block window's voxQ working set stays L2/L3 resident).
__global__ __launch_bounds__(512) void fused_kernel(const uint2v* __restrict__ voxQ,
                                                    const float* __restrict__ verts,
                                                    const unsigned short* __restrict__ Wp,
                                                    const float* __restrict__ bias,
                                                    const int* __restrict__ perm,
                                                    float* __restrict__ out) {
    __shared__ __align__(16) unsigned short At[16 * AST];
    __shared__ int vids[16];
    int tid = threadIdx.x;
    int vl = tid >> 5;               // vertex-slot-in-block 0..15
    int c = tid & 31;                // channel
    if (tid < 16) vids[tid] = perm[(int)blockIdx.x * 16 + tid];
    __syncthreads();
    int vid = vids[vl];

    const float* vp = verts + (size_t)vid * 3;
    float vx = vp[0], vy = vp[1], vz = vp[2];
    const float sc = 2.0f / 95.0f;
    int wsx, wsy, wsz;
    float wx[3][4], wy[3][4], wz[3][4];
    axis_setup(vx, sc, wsx, wx);  // x -> D axis (innermost spatial)
    axis_setup(vy, sc, wsy, wy);  // y -> W axis
    axis_setup(vz, sc, wsz, wz);  // z -> H axis

    // 7-wide x-weights: wx7[a][o + j] = wx[a][j], o = wsx & 3 (static-index shifts)
    int o = wsx & 3;
    bool s1 = (o & 1) != 0, s2 = (o & 2) != 0;
    float wx7[3][7];
#pragma unroll
    for (int a = 0; a < 3; ++a) {
        float t0 = s1 ? 0.0f : wx[a][0];
        float t1 = s1 ? wx[a][0] : wx[a][1];
        float t2 = s1 ? wx[a][1] : wx[a][2];
        float t3 = s1 ? wx[a][2] : wx[a][3];
        float t4 = s1 ? wx[a][3] : 0.0f;
        wx7[a][0] = s2 ? 0.0f : t0;
        wx7[a][1] = s2 ? 0.0f : t1;
        wx7[a][2] = s2 ? t0 : t2;
        wx7[a][3] = s2 ? t1 : t3;
        wx7[a][4] = s2 ? t2 : t4;
        wx7[a][5] = s2 ? t3 : 0.0f;
        wx7[a][6] = s2 ? t4 : 0.0f;
    }
    int q0 = wsx >> 2;
    int q1 = min(q0 + 1, 23);        // clamp: when q0==23, o==0 so quad-2 weights are 0

    int bb = (vid >= NV) ? 1 : 0;
    const uint2v* Qb = voxQ + (size_t)bb * 9216 * 768 + c;

    float f[27];
#pragma unroll
    for (int k = 0; k < 27; ++k) f[k] = 0.0f;

#pragma unroll
    for (int tz = 0; tz < 4; ++tz) {
        float ry[9];
#pragma unroll
        for (int i = 0; i < 9; ++i) ry[i] = 0.0f;
#pragma unroll
        for (int ty = 0; ty < 4; ++ty) {
            size_t r = ((size_t)(wsz + tz) * 96 + (size_t)(wsy + ty)) * 24;
            uint2v A = Qb[(r + q0) * 32];
            uint2v Bq = Qb[(r + q1) * 32];
            float b0 = bf_lo(A[0]), b1 = bf_hi(A[0]), b2 = bf_lo(A[1]), b3 = bf_hi(A[1]);
            float b4 = bf_lo(Bq[0]), b5 = bf_hi(Bq[0]), b6 = bf_lo(Bq[1]);
#pragma unroll
            for (int a = 0; a < 3; ++a) {
                float rxt = b0 * wx7[a][0] + b1 * wx7[a][1] + b2 * wx7[a][2] +
                            b3 * wx7[a][3] + b4 * wx7[a][4] + b5 * wx7[a][5] +
                            b6 * wx7[a][6];
#pragma unroll
                for (int b = 0; b < 3; ++b)
                    ry[3 * b + a] = fmaf(rxt, wy[b][ty], ry[3 * b + a]);
            }
        }
#pragma unroll
        for (int g = 0; g < 3; ++g)
#pragma unroll
            for (int b = 0; b < 3; ++b)
#pragma unroll
                for (int a = 0; a < 3; ++a)
                    f[9 * a + 3 * b + g] = fmaf(ry[3 * b + a], wz[g][tz], f[9 * a + 3 * b + g]);
    }

    // Pack 27+5pad taps into 4 16B units; unit j stored at rotate-swizzled slot
    // c*4 + ((j + c) & 3) to spread LDS write bank groups.
    unsigned short* rowp = &At[vl * AST];
#pragma unroll
    for (int j = 0; j < 4; ++j) {
        const int kb = j * 8;
        unsigned int pw[4];
#pragma unroll
        for (int t2 = 0; t2 < 4; ++t2) {
            int k0 = kb + 2 * t2, k1 = k0 + 1;
            float lo = (k0 < 27) ? f[k0] : 0.0f;
            float hi = (k1 < 27) ? f[k1] : 0.0f;
            pw[t2] = (unsigned int)f2bf(lo) | ((unsigned int)f2bf(hi) << 16);
        }
        uint4v s = {pw[0], pw[1], pw[2], pw[3]};
        int p = c * 4 + ((j + c) & 3);
        *(uint4v*)(rowp + p * 8) = s;
    }

    __syncthreads();

    int wv = tid >> 6;               // wave id 0..7; waves 0,1 do the GEMM
    if (wv < 2) {
        int lane = tid & 63;
        int mrow = lane & 15, quad = lane >> 4;
        const bf16x8* wp = (const bf16x8*)Wp;
        f32x4 acc = {0.f, 0.f, 0.f, 0.f};
#pragma unroll 8
        for (int s = 0; s < 32; ++s) {
            int p = s * 4 + ((quad + s) & 3);     // un-swizzle (c=s, j=quad)
            bf16x8 a = *(const bf16x8*)&At[mrow * AST + p * 8];
            bf16x8 b = wp[(s * 2 + wv) * 64 + lane];
            acc = __builtin_amdgcn_mfma_f32_16x16x32_bf16(a, b, acc, 0, 0, 0);
        }
        float bs = bias[wv * 16 + mrow];
#pragma unroll
        for (int r = 0; r < 4; ++r) {
            int vrow = vids[quad * 4 + r];
            out[(size_t)vrow * 32 + wv * 16 + mrow] = acc[r] + bs;
        }
    }
}

extern "C" void kernel_launch(void* const* d_in, const int* in_sizes, int n_in,
                              void* d_out, int out_size, void* d_ws, size_t ws_size,
                              hipStream_t stream) {
    const float* vox = (const float*)d_in[0];
    const float* verts = (const float*)d_in[1];
    const float* cw = (const float*)d_in[2];
    const float* cb = (const float*)d_in[3];
    float* out = (float*)d_out;

    // ws layout: Wp 64KB | cursors 1KB | perm 240KB(+pad) | voxQ 113.25 MB
    char* wsp = (char*)d_ws;
    unsigned short* Wp = (unsigned short*)wsp;
    int* cursors = (int*)(wsp + 65536);
    int* perm = (int*)(wsp + 65536 + 1024);
    uint2v* voxQ = (uint2v*)(wsp + 65536 + 1024 + 245760);

    hipLaunchKernelGGL(prep_kernel, dim3(128), dim3(256), 0, stream, cw, Wp);
    hipLaunchKernelGGL(count_kernel, dim3(1), dim3(256), 0, stream, verts, cursors);
    hipLaunchKernelGGL(scatter_kernel, dim3((NVT + 255) / 256), dim3(256), 0, stream,
                       verts, cursors, perm);
    hipLaunchKernelGGL(transpose_kernel, dim3(18432), dim3(256), 0, stream, vox, voxQ);
    hipLaunchKernelGGL(fused_kernel, dim3(3750), dim3(512), 0, stream,
                       voxQ, verts, Wp, cb, perm, out);
}

// Round 6
// 420.405 us; speedup vs baseline: 1.4336x; 1.4336x over previous
//
#include <hip/hip_runtime.h>
#include <stdint.h>

// Problem constants (fixed by setup_inputs): B=2, C=32, H=W=D=96, N=30000
#define HWD 884736ull          // 96*96*96
#define NV 30000               // vertices per batch
#define AST 1032               // LDS A-tile row stride (shorts); breaks pow2 strides

typedef __attribute__((ext_vector_type(8))) __bf16 bf16x8;
typedef __attribute__((ext_vector_type(2))) __bf16 bf16x2;
typedef __attribute__((ext_vector_type(4))) float f32x4;
typedef __attribute__((ext_vector_type(2))) float f32x2;
typedef __attribute__((ext_vector_type(2))) unsigned int uint2v;
typedef __attribute__((ext_vector_type(4))) unsigned int uint4v;

__device__ __forceinline__ unsigned short f2bf(float f) {
    union { float f; unsigned int u; } v; v.f = f;
    unsigned int u = v.u;
    return (unsigned short)((u + 0x7FFFu + ((u >> 16) & 1u)) >> 16);  // RNE
}

__device__ __forceinline__ float bf_lo(unsigned int u) {
    union { unsigned int u; float f; } v; v.u = u << 16; return v.f;
}
__device__ __forceinline__ float bf_hi(unsigned int u) {
    union { unsigned int u; float f; } v; v.u = u & 0xffff0000u; return v.f;
}

// acc += u.lo*w.lo + u.hi*w.hi with f32 accumulate (V_DOT2_F32_BF16 if available)
__device__ __forceinline__ float dot2bf(unsigned int u, unsigned int w, float acc) {
#if __has_builtin(__builtin_amdgcn_fdot2_f32_bf16)
    return __builtin_amdgcn_fdot2_f32_bf16(__builtin_bit_cast(bf16x2, u),
                                           __builtin_bit_cast(bf16x2, w), acc, false);
#else
    return fmaf(bf_hi(u), bf_hi(w), fmaf(bf_lo(u), bf_lo(w), acc));
#endif
}

// Per-axis: replicate reference clamp/floor math for shifts {-1,0,1}, then fold
// into 4-wide window weights. Window start ws = clamp(x0_center-1, 0, 92).
__device__ __forceinline__ void axis_setup(float coord, float sc, int& wstart, float w[3][4]) {
    int i0[3], i1[3];
    float fr[3];
#pragma unroll
    for (int a = 0; a < 3; ++a) {
        float g = coord + (float)(a - 1) * sc;
        float ix = (g + 1.0f) * 0.5f * 95.0f;
        ix = fminf(fmaxf(ix, 0.0f), 95.0f);
        float fl = floorf(ix);
        int x0 = (int)fl;
        i0[a] = x0;
        i1[a] = min(x0 + 1, 95);
        fr[a] = ix - fl;
    }
    int ws = min(max(i0[1] - 1, 0), 92);
    wstart = ws;
#pragma unroll
    for (int a = 0; a < 3; ++a) {
        int d0 = min(max(i0[a] - ws, 0), 3);
        int d1 = min(max(i1[a] - ws, 0), 3);
        float f1 = fr[a], f0 = 1.0f - f1;
#pragma unroll
        for (int j = 0; j < 4; ++j)
            w[a][j] = (d0 == j ? f0 : 0.0f) + (d1 == j ? f1 : 0.0f);
    }
}

// Pack conv_w (32,32,1,27) fp32 -> bf16 B-fragments for mfma_f32_16x16x32_bf16.
// element j of wp[(s*2+t)*64 + lane] is B[k = s*32 + (lane>>4)*8 + j][o = t*16 + (lane&15)]
__global__ __launch_bounds__(256) void prep_kernel(const float* __restrict__ cw,
                                                   unsigned short* __restrict__ Wp) {
    int gid = blockIdx.x * 256 + threadIdx.x;  // 0..32767
    int j = gid & 7;
    int l = (gid >> 3) & 63;
    int t = (gid >> 9) & 1;
    int s = gid >> 10;
    int kk = ((l >> 4) & 3) * 8 + j;
    int o = t * 16 + (l & 15);
    float v = 0.0f;
    if (kk < 27) v = cw[(size_t)o * 864 + s * 27 + kk];
    Wp[gid] = f2bf(v);
}

// (B,C,H,W,D) fp32 -> x-quad-packed bf16: voxQ[((b*9216+zy)*24 + q)*32 + c] is a
// uint2 holding taps x = 4q..4q+3 of channel c (2 bf16 per uint, low = even x).
__global__ __launch_bounds__(256) void transpose_kernel(const float* __restrict__ vox,
                                                        uint2v* __restrict__ voxQ) {
    int blk = blockIdx.x;            // 0..18431 encodes (b, zy)
    int tid = threadIdx.x;
    int b = blk / 9216;
    int zy = blk % 9216;
    const float* src = vox + (size_t)b * 32 * HWD + (size_t)zy * 96;
    uint2v* dst = voxQ + (size_t)blk * 768;
#pragma unroll
    for (int i = 0; i < 3; ++i) {
        int idx = i * 256 + tid;     // 0..767
        int c = idx & 31;
        int q = idx >> 5;            // 0..23
        f32x4 v = *(const f32x4*)(src + (size_t)c * HWD + q * 4);
        unsigned int u0 = (unsigned int)f2bf(v[0]) | ((unsigned int)f2bf(v[1]) << 16);
        unsigned int u1 = (unsigned int)f2bf(v[2]) | ((unsigned int)f2bf(v[3]) << 16);
        uint2v p = {u0, u1};
        dst[q * 32 + c] = p;
    }
}

// Fused sample + GEMM. Block = 512 threads = 16 vertices x 32 channels.
// Register-double-buffered over tz: the next z-layer's 8 row-loads are issued
// before consuming the current layer (8 loads in flight), so the ~200-cyc
// per-layer dot2/pk-fma block overlaps memory latency across 4 waves/SIMD.
__global__ __launch_bounds__(512, 4) void fused_kernel(const uint2v* __restrict__ voxQ,
                                                       const float* __restrict__ verts,
                                                       const unsigned short* __restrict__ Wp,
                                                       const float* __restrict__ bias,
                                                       float* __restrict__ out) {
    __shared__ __align__(16) unsigned short At[16 * AST];
    int tid = threadIdx.x;
    int vl = tid >> 5;               // vertex-in-block 0..15
    int c = tid & 31;                // channel
    int vg = (int)blockIdx.x * 16 + vl;   // 3750*16 = 60000 exactly

    const float* vp = verts + (size_t)vg * 3;
    float vx = vp[0], vy = vp[1], vz = vp[2];
    const float sc = 2.0f / 95.0f;
    int wsx, wsy, wsz;
    float wx[3][4], wy[3][4], wz[3][4];
    axis_setup(vx, sc, wsx, wx);  // x -> D axis (innermost spatial)
    axis_setup(vy, sc, wsy, wy);  // y -> W axis
    axis_setup(vz, sc, wsz, wz);  // z -> H axis

    // x-window weights as bf16 pairs in an 8-halfword window shifted by o=wsx&3:
    // wxp[a][j] holds (wx7[2j], wx7[2j+1]) where wx7[o+i] = wx[a][i].
    unsigned int wxp[3][4];
    {
        int o = wsx & 3;
        bool s1 = (o & 1) != 0, s2 = (o & 2) != 0;
#pragma unroll
        for (int a = 0; a < 3; ++a) {
            unsigned int w01 = (unsigned int)f2bf(wx[a][0]) | ((unsigned int)f2bf(wx[a][1]) << 16);
            unsigned int w23 = (unsigned int)f2bf(wx[a][2]) | ((unsigned int)f2bf(wx[a][3]) << 16);
            unsigned int a0 = s1 ? (w01 << 16) : w01;
            unsigned int a1 = s1 ? ((w01 >> 16) | (w23 << 16)) : w23;
            unsigned int a2 = s1 ? (w23 >> 16) : 0u;
            wxp[a][0] = s2 ? 0u : a0;
            wxp[a][1] = s2 ? a0 : a1;
            wxp[a][2] = s2 ? a1 : a2;
            wxp[a][3] = s2 ? a2 : 0u;
        }
    }
    // y/z weights packed as f32 pairs (index 0,1) + scalar (index 2) -> v_pk_fma_f32
    f32x2 wyp[4], wzp[4];
    float wy2[4], wz2[4];
#pragma unroll
    for (int t = 0; t < 4; ++t) {
        wyp[t] = (f32x2){wy[0][t], wy[1][t]}; wy2[t] = wy[2][t];
        wzp[t] = (f32x2){wz[0][t], wz[1][t]}; wz2[t] = wz[2][t];
    }

    int q0 = wsx >> 2;
    int qd = (q0 < 23) ? 256 : 0;    // byte delta to second quad (0 at edge; weights 0 there)
    int bb = (vg >= NV) ? 1 : 0;
    // byte offset of (zy, q, c): zy*6144 + q*256 + c*8 ; z stride 589824
    const char* pb = (const char*)voxQ + (size_t)bb * 56623104ull +
                     (size_t)wsz * 589824 + (size_t)wsy * 6144 + (size_t)q0 * 256 + c * 8;

    uint2v bufA[2][4], bufB[2][4];
#pragma unroll
    for (int ty = 0; ty < 4; ++ty) {
        const char* pr = pb + ty * 6144;
        bufA[0][ty] = *(const uint2v*)pr;
        bufB[0][ty] = *(const uint2v*)(pr + qd);
    }

    f32x2 fp[9];
    float fs[9];
#pragma unroll
    for (int i = 0; i < 9; ++i) { fp[i] = (f32x2){0.f, 0.f}; fs[i] = 0.f; }

#pragma unroll
    for (int tz = 0; tz < 4; ++tz) {
        const int cur = tz & 1;
        if (tz < 3) {                // prefetch next z-layer before consuming current
            const char* pn = pb + (size_t)(tz + 1) * 589824;
            const int nxt = cur ^ 1;
#pragma unroll
            for (int ty = 0; ty < 4; ++ty) {
                const char* pr = pn + ty * 6144;
                bufA[nxt][ty] = *(const uint2v*)pr;
                bufB[nxt][ty] = *(const uint2v*)(pr + qd);
            }
        }
        f32x2 ryp[3];
        float rys[3];
#pragma unroll
        for (int a = 0; a < 3; ++a) { ryp[a] = (f32x2){0.f, 0.f}; rys[a] = 0.f; }
#pragma unroll
        for (int ty = 0; ty < 4; ++ty) {
            unsigned int A0 = bufA[cur][ty][0], A1 = bufA[cur][ty][1];
            unsigned int B0 = bufB[cur][ty][0], B1 = bufB[cur][ty][1];
#pragma unroll
            for (int a = 0; a < 3; ++a) {
                float r = dot2bf(B1, wxp[a][3], 0.0f);
                r = dot2bf(B0, wxp[a][2], r);
                r = dot2bf(A1, wxp[a][1], r);
                r = dot2bf(A0, wxp[a][0], r);
                f32x2 rr = {r, r};
                ryp[a] = rr * wyp[ty] + ryp[a];
                rys[a] = fmaf(r, wy2[ty], rys[a]);
            }
        }
#pragma unroll
        for (int a = 0; a < 3; ++a)
#pragma unroll
            for (int b = 0; b < 3; ++b) {
                float rv = (b < 2) ? ryp[a][b] : rys[a];
                f32x2 rr = {rv, rv};
                fp[3 * a + b] = rr * wzp[tz] + fp[3 * a + b];
                fs[3 * a + b] = fmaf(rv, wz2[tz], fs[3 * a + b]);
            }
    }

    // Reassemble tap order k = 9a+3b+g (g in {0,1} from fp, g=2 from fs)
    float ff[27];
#pragma unroll
    for (int a = 0; a < 3; ++a)
#pragma unroll
        for (int b = 0; b < 3; ++b) {
            ff[9 * a + 3 * b + 0] = fp[3 * a + b][0];
            ff[9 * a + 3 * b + 1] = fp[3 * a + b][1];
            ff[9 * a + 3 * b + 2] = fs[3 * a + b];
        }

    // Pack 27+5pad taps into 4 16B units; unit j stored at rotate-swizzled slot
    // c*4 + ((j + c) & 3) to spread LDS write bank groups.
    unsigned short* rowp = &At[vl * AST];
#pragma unroll
    for (int j = 0; j < 4; ++j) {
        const int kb = j * 8;
        unsigned int pw[4];
#pragma unroll
        for (int t2 = 0; t2 < 4; ++t2) {
            int k0 = kb + 2 * t2, k1 = k0 + 1;
            float lo = (k0 < 27) ? ff[k0] : 0.0f;
            float hi = (k1 < 27) ? ff[k1] : 0.0f;
            pw[t2] = (unsigned int)f2bf(lo) | ((unsigned int)f2bf(hi) << 16);
        }
        uint4v s = {pw[0], pw[1], pw[2], pw[3]};
        int p = c * 4 + ((j + c) & 3);
        *(uint4v*)(rowp + p * 8) = s;
    }

    __syncthreads();

    int wv = tid >> 6;               // wave id 0..7; waves 0,1 do the GEMM
    if (wv < 2) {
        int lane = tid & 63;
        int mrow = lane & 15, quad = lane >> 4;
        const bf16x8* wp = (const bf16x8*)Wp;
        f32x4 acc = {0.f, 0.f, 0.f, 0.f};
#pragma unroll 8
        for (int s = 0; s < 32; ++s) {
            int p = s * 4 + ((quad + s) & 3);     // un-swizzle (c=s, j=quad)
            bf16x8 a = *(const bf16x8*)&At[mrow * AST + p * 8];
            bf16x8 b = wp[(s * 2 + wv) * 64 + lane];
            acc = __builtin_amdgcn_mfma_f32_16x16x32_bf16(a, b, acc, 0, 0, 0);
        }
        float bs = bias[wv * 16 + mrow];
#pragma unroll
        for (int r = 0; r < 4; ++r) {
            int v = (int)blockIdx.x * 16 + quad * 4 + r;
            out[(size_t)v * 32 + wv * 16 + mrow] = acc[r] + bs;
        }
    }
}

extern "C" void kernel_launch(void* const* d_in, const int* in_sizes, int n_in,
                              void* d_out, int out_size, void* d_ws, size_t ws_size,
                              hipStream_t stream) {
    const float* vox = (const float*)d_in[0];
    const float* verts = (const float*)d_in[1];
    const float* cw = (const float*)d_in[2];
    const float* cb = (const float*)d_in[3];
    float* out = (float*)d_out;

    // ws layout: Wp (64 KB) | voxQ bf16 quad-packed (2*HWD*32*2 = 113.25 MB).
    unsigned short* Wp = (unsigned short*)d_ws;
    uint2v* voxQ = (uint2v*)((char*)d_ws + 65536);

    hipLaunchKernelGGL(prep_kernel, dim3(128), dim3(256), 0, stream, cw, Wp);
    hipLaunchKernelGGL(transpose_kernel, dim3(18432), dim3(256), 0, stream, vox, voxQ);
    hipLaunchKernelGGL(fused_kernel, dim3(3750), dim3(512), 0, stream,
                       voxQ, verts, Wp, cb, out);
}